// Round 6
// baseline (504.164 us; speedup 1.0000x reference)
//
#include <hip/hip_runtime.h>
#include <stdint.h>

#define NAT 65536
#define CH 512
#define NQKV 768

typedef __bf16 bf16x8 __attribute__((ext_vector_type(8)));
typedef float f32x4 __attribute__((ext_vector_type(4)));

union B8 { uint4 u; __bf16 h[8]; };

__device__ __forceinline__ void gload16(const void* g, void* l) {
  __builtin_amdgcn_global_load_lds((const __attribute__((address_space(1))) void*)g,
                                   (__attribute__((address_space(3))) void*)l, 16, 0, 0);
}

// ---------------- prep: fp32 -> bf16 conversions + stats zero ----------------
__global__ void k_prep(const float* __restrict__ atom, const float* __restrict__ wqk,
                       const float* __restrict__ bqk, const float* __restrict__ wv,
                       const float* __restrict__ bv, const float* __restrict__ wt,
                       __bf16* __restrict__ atom16, __bf16* __restrict__ wqkv16,
                       float* __restrict__ bqkv, __bf16* __restrict__ wt16,
                       float* __restrict__ stats)
{
  int tid = blockIdx.x * blockDim.x + threadIdx.x;
  int nth = gridDim.x * blockDim.x;
  const float4* a4 = (const float4*)atom;
  for (int i = tid; i < NAT * CH / 8; i += nth) {
    float4 x = a4[2 * i], y = a4[2 * i + 1];
    B8 u;
    u.h[0] = (__bf16)x.x; u.h[1] = (__bf16)x.y; u.h[2] = (__bf16)x.z; u.h[3] = (__bf16)x.w;
    u.h[4] = (__bf16)y.x; u.h[5] = (__bf16)y.y; u.h[6] = (__bf16)y.z; u.h[7] = (__bf16)y.w;
    ((uint4*)atom16)[i] = u.u;
  }
  for (int i = tid; i < NQKV * CH / 8; i += nth) {
    int row = (i * 8) >> 9;
    const float* src = (row < 256) ? (wqk + (size_t)i * 8) : (wv + (size_t)i * 8 - 256 * 512);
    float4 x = ((const float4*)src)[0], y = ((const float4*)src)[1];
    B8 u;
    u.h[0] = (__bf16)x.x; u.h[1] = (__bf16)x.y; u.h[2] = (__bf16)x.z; u.h[3] = (__bf16)x.w;
    u.h[4] = (__bf16)y.x; u.h[5] = (__bf16)y.y; u.h[6] = (__bf16)y.z; u.h[7] = (__bf16)y.w;
    ((uint4*)wqkv16)[i] = u.u;
  }
  for (int i = tid; i < CH * CH / 8; i += nth) {
    float4 x = ((const float4*)wt)[2 * i], y = ((const float4*)wt)[2 * i + 1];
    B8 u;
    u.h[0] = (__bf16)x.x; u.h[1] = (__bf16)x.y; u.h[2] = (__bf16)x.z; u.h[3] = (__bf16)x.w;
    u.h[4] = (__bf16)y.x; u.h[5] = (__bf16)y.y; u.h[6] = (__bf16)y.z; u.h[7] = (__bf16)y.w;
    ((uint4*)wt16)[i] = u.u;
  }
  if (tid < NQKV) bqkv[tid] = (tid < 256) ? bqk[tid] : bv[tid - 256];
  if (tid < 1024) stats[tid] = 0.f;
}

// ---------------- GEMM: C[M,NOUT] = A[M,512] @ W[NOUT,512]^T + bias ----------------
// 128x256 tile, BK=64, 8 waves (2x4 of 64x64), single 48KB LDS buffer, 3 blocks/CU by LDS.
// T3-min overlap: ds_read all frags -> lgkmcnt(0)+barrier (buffer free) -> issue
// next-tile global_load_lds into SAME buffer -> MFMA under the loads -> vmcnt(0)+barrier.
template<int NOUT, bool STATS>
__global__ __launch_bounds__(512) void k_gemm(const __bf16* __restrict__ A,
    const __bf16* __restrict__ W, const float* __restrict__ bias,
    __bf16* __restrict__ Cout, float* __restrict__ stats)
{
  __shared__ __align__(16) char lds[49152];   // A 16KB + B 32KB
  const int t = threadIdx.x, w = t >> 6, l = t & 63;
  const int wr = w >> 2, wc = w & 3;          // wave grid 2(M) x 4(N)
  const int m0 = blockIdx.x * 128, n0 = blockIdx.y * 256;
  const int lrow = l >> 3;                    // 0..7
  const int lslot = (l & 7) ^ lrow;           // pre-swizzled global 16B-slot
  f32x4 acc[4][4] = {};

  auto stage = [&](int kt) {
    const int k0 = kt * 64;
#pragma unroll
    for (int i = 0; i < 2; ++i) {             // A: 16 chunks of 1KB, 8 waves x 2
      int row = (i * 8 + w) * 8 + lrow;       // 0..127
      gload16(A + ((size_t)(m0 + row) * 512 + k0 + lslot * 8), lds + (i * 8 + w) * 1024);
    }
#pragma unroll
    for (int i = 0; i < 4; ++i) {             // B: 32 chunks, 8 waves x 4
      int row = (i * 8 + w) * 8 + lrow;       // 0..255
      gload16(W + ((size_t)(n0 + row) * 512 + k0 + lslot * 8), lds + 16384 + (i * 8 + w) * 1024);
    }
  };

  stage(0);
  asm volatile("s_waitcnt vmcnt(0)" ::: "memory");
  __builtin_amdgcn_s_barrier();

  for (int kt = 0; kt < 8; ++kt) {
    // read ALL fragments of this K-step into registers
    bf16x8 af[2][4], bfr[2][4];
#pragma unroll
    for (int ks = 0; ks < 2; ++ks) {
#pragma unroll
      for (int mi = 0; mi < 4; ++mi) {
        int r = wr * 64 + mi * 16 + (l & 15);
        af[ks][mi] = *(const bf16x8*)(lds + r * 128 + (((ks * 4 + (l >> 4)) ^ (r & 7)) << 4));
      }
#pragma unroll
      for (int ni = 0; ni < 4; ++ni) {
        int r = wc * 64 + ni * 16 + (l & 15);
        bfr[ks][ni] = *(const bf16x8*)(lds + 16384 + r * 128 + (((ks * 4 + (l >> 4)) ^ (r & 7)) << 4));
      }
    }
    asm volatile("s_waitcnt lgkmcnt(0)" ::: "memory");   // my reads done
    __builtin_amdgcn_s_barrier();                        // everyone's reads done -> buffer free
    if (kt < 7) stage(kt + 1);                           // refill under the MFMAs
    __builtin_amdgcn_s_setprio(1);
#pragma unroll
    for (int ks = 0; ks < 2; ++ks)
#pragma unroll
      for (int ni = 0; ni < 4; ++ni)
#pragma unroll
        for (int mi = 0; mi < 4; ++mi)
          acc[mi][ni] = __builtin_amdgcn_mfma_f32_16x16x32_bf16(af[ks][mi], bfr[ks][ni], acc[mi][ni], 0, 0, 0);
    __builtin_amdgcn_s_setprio(0);
    if (kt < 7) {
      asm volatile("s_waitcnt vmcnt(0)" ::: "memory");   // residual drain after MFMAs
      __builtin_amdgcn_s_barrier();
    }
  }

  // epilogue: bias (+stats), direct stores
  float ssum[4] = {0, 0, 0, 0}, ssq[4] = {0, 0, 0, 0};
#pragma unroll
  for (int ni = 0; ni < 4; ++ni) {
    int col = n0 + wc * 64 + ni * 16 + (l & 15);
    float bb = bias[col];
#pragma unroll
    for (int mi = 0; mi < 4; ++mi) {
#pragma unroll
      for (int r = 0; r < 4; ++r) {
        int row = m0 + wr * 64 + mi * 16 + (l >> 4) * 4 + r;
        float v = acc[mi][ni][r] + bb;
        Cout[(size_t)row * NOUT + col] = (__bf16)v;
        if (STATS) { ssum[ni] += v; ssq[ni] += v * v; }
      }
    }
  }
  if (STATS) {
#pragma unroll
    for (int ni = 0; ni < 4; ++ni) {
      float s = ssum[ni], q = ssq[ni];
      s += __shfl_xor(s, 16, 64); q += __shfl_xor(q, 16, 64);
      s += __shfl_xor(s, 32, 64); q += __shfl_xor(q, 32, 64);
      if (l < 16) {
        int col = n0 + wc * 64 + ni * 16 + l;
        atomicAdd(&stats[col], s);
        atomicAdd(&stats[512 + col], q);
      }
    }
  }
}

// ---------------- per-crystal attention ----------------
__global__ __launch_bounds__(256, 2) void k_attn(const __bf16* __restrict__ qkv,
    const __bf16* __restrict__ atom16, __bf16* __restrict__ xt)
{
  __shared__ __align__(16) char sm[49920];
  float* E = (float*)(sm + 32768);         // [64][65] f32 (padded)
  float* colinv = (float*)(sm + 49408);    // [64]
  float* rowinv = (float*)(sm + 49664);    // [64]
  const int t = threadIdx.x, w = t >> 6, l = t & 63;
  const size_t g0 = (size_t)blockIdx.x * 64;

#pragma unroll
  for (int i = 0; i < 8; ++i) {
    int chunk = i * 256 + t;
    int row = chunk >> 5, slot = chunk & 31;
    uint4 d = *(const uint4*)(qkv + (g0 + row) * NQKV + slot * 8);
    *(uint4*)(sm + row * 512 + ((slot ^ (row & 7)) << 4)) = d;
  }
  __syncthreads();

  f32x4 eacc[4] = {};
#pragma unroll
  for (int kk = 0; kk < 8; ++kk) {
    int ra = 16 * w + (l & 15);
    bf16x8 af = *(const bf16x8*)(sm + ra * 512 + (((kk * 4 + (l >> 4)) ^ (ra & 7)) << 4));
#pragma unroll
    for (int nj = 0; nj < 4; ++nj) {
      int rb = 16 * nj + (l & 15);
      bf16x8 bf_ = *(const bf16x8*)(sm + rb * 512 + (((kk * 4 + (l >> 4)) ^ (rb & 7)) << 4));
      eacc[nj] = __builtin_amdgcn_mfma_f32_16x16x32_bf16(af, bf_, eacc[nj], 0, 0, 0);
    }
  }
#pragma unroll
  for (int nj = 0; nj < 4; ++nj)
#pragma unroll
    for (int r = 0; r < 4; ++r) {
      int i = 16 * w + (l >> 4) * 4 + r;
      int j = 16 * nj + (l & 15);
      E[i * 65 + j] = eacc[nj][r] * 0.0625f;
    }
  __syncthreads();

  auto stage_v = [&](int h) {
#pragma unroll
    for (int ch = 0; ch < 8; ++ch) {
      int cb = w * 64 + ch * 8;
      B8 d; d.u = *(const uint4*)(qkv + (g0 + l) * NQKV + 256 + h * 256 + cb);
#pragma unroll
      for (int e = 0; e < 8; ++e) {
        int c = cb + e;
        *(__bf16*)(sm + c * 128 + (((l >> 3) ^ (c & 7)) << 4) + (l & 7) * 2) = d.h[e];
      }
    }
  };

  stage_v(0);

  {  // softmax over query axis i, per column j; 4-lane quad per column
    int j = t >> 2, sub = t & 3;
    float m = -1e30f;
#pragma unroll
    for (int k = 0; k < 16; ++k) m = fmaxf(m, E[(sub + 4 * k) * 65 + j]);
    m = fmaxf(m, __shfl_xor(m, 1)); m = fmaxf(m, __shfl_xor(m, 2));
    float s = 0.f;
#pragma unroll
    for (int k = 0; k < 16; ++k) {
      float e = __expf(E[(sub + 4 * k) * 65 + j] - m);
      E[(sub + 4 * k) * 65 + j] = e; s += e;
    }
    s += __shfl_xor(s, 1); s += __shfl_xor(s, 2);
    if (sub == 0) colinv[j] = 1.f / s;
  }
  __syncthreads();
  {  // L1 over keys j, per row i
    int i = t >> 2, sub = t & 3;
    float rs = 0.f;
#pragma unroll
    for (int k = 0; k < 16; ++k) { int j = sub + 4 * k; rs += E[i * 65 + j] * colinv[j]; }
    rs += __shfl_xor(rs, 1); rs += __shfl_xor(rs, 2);
    if (sub == 0) rowinv[i] = 1.f / (1e-9f + rs);
  }
  __syncthreads();

  auto pv_out = [&](int h) {
    f32x4 acc[4][4] = {};
#pragma unroll
    for (int ks = 0; ks < 2; ++ks) {
      bf16x8 af[4];
#pragma unroll
      for (int mi = 0; mi < 4; ++mi) {
        int i = mi * 16 + (l & 15);
        float ri = rowinv[i];
        bf16x8 a;
#pragma unroll
        for (int e = 0; e < 8; ++e) {
          int j = ks * 32 + (l >> 4) * 8 + e;
          a[e] = (__bf16)(E[i * 65 + j] * colinv[j] * ri);
        }
        af[mi] = a;
      }
#pragma unroll
      for (int nc = 0; nc < 4; ++nc) {
        int c = w * 64 + nc * 16 + (l & 15);
        bf16x8 bfr = *(const bf16x8*)(sm + c * 128 + (((ks * 4 + (l >> 4)) ^ (c & 7)) << 4));
#pragma unroll
        for (int mi = 0; mi < 4; ++mi)
          acc[mi][nc] = __builtin_amdgcn_mfma_f32_16x16x32_bf16(af[mi], bfr, acc[mi][nc], 0, 0, 0);
      }
    }
    __syncthreads();
#pragma unroll
    for (int mi = 0; mi < 4; ++mi)
#pragma unroll
      for (int nc = 0; nc < 4; ++nc)
#pragma unroll
        for (int r = 0; r < 4; ++r) {
          int i = mi * 16 + (l >> 4) * 4 + r;
          int c = w * 64 + nc * 16 + (l & 15);
          int s = c >> 3;
          *(__bf16*)(sm + i * 512 + (((s ^ (i & 7))) << 4) + (c & 7) * 2) = (__bf16)acc[mi][nc][r];
        }
    __syncthreads();
#pragma unroll
    for (int j = 0; j < 8; ++j) {
      int chunk = j * 256 + t;
      int row = chunk >> 5, p = chunk & 31;
      int s = p ^ (row & 7);
      B8 xv; xv.u = *(const uint4*)(sm + row * 512 + p * 16);
      B8 av; av.u = *(const uint4*)(atom16 + (g0 + row) * 512 + h * 256 + s * 8);
      B8 o;
#pragma unroll
      for (int e = 0; e < 8; ++e) o.h[e] = (__bf16)((float)av.h[e] - (float)xv.h[e]);
      *(uint4*)(xt + (g0 + row) * 512 + h * 256 + s * 8) = o.u;
    }
  };

  pv_out(0);
  __syncthreads();
  stage_v(1);
  __syncthreads();
  pv_out(1);
}

// ---------------- final: out = atom + relu(t*scale + shift), stats inlined ----------------
__global__ void k_final(const float* __restrict__ atom, const __bf16* __restrict__ tmat,
                        const float* __restrict__ stats, const float* __restrict__ gamma,
                        const float* __restrict__ beta, float* __restrict__ out)
{
  int tid = blockIdx.x * blockDim.x + threadIdx.x;
  int nth = gridDim.x * blockDim.x;
  const float invn = 1.f / NAT;
  for (int i = tid; i < NAT * CH / 8; i += nth) {
    int colb = (i & 63) * 8;
    B8 tv; tv.u = ((const uint4*)tmat)[i];
    float4 a0 = ((const float4*)atom)[2 * i], a1 = ((const float4*)atom)[2 * i + 1];
    float4 o0, o1;
#pragma unroll
    for (int e = 0; e < 8; ++e) {
      int c = colb + e;
      float mean = stats[c] * invn;
      float var = stats[512 + c] * invn - mean * mean;
      float sc = gamma[c] * rsqrtf(var + 1e-5f);
      float sh = beta[c] - mean * sc;
      float av = (e < 4) ? ((const float*)&a0)[e] : ((const float*)&a1)[e - 4];
      float v = av + fmaxf(0.f, (float)tv.h[e] * sc + sh);
      if (e < 4) ((float*)&o0)[e] = v; else ((float*)&o1)[e - 4] = v;
    }
    ((float4*)out)[2 * i] = o0;
    ((float4*)out)[2 * i + 1] = o1;
  }
}

extern "C" void kernel_launch(void* const* d_in, const int* in_sizes, int n_in,
                              void* d_out, int out_size, void* d_ws, size_t ws_size,
                              hipStream_t stream) {
  const float* atom  = (const float*)d_in[0];
  const float* wqk   = (const float*)d_in[1];
  const float* bqk   = (const float*)d_in[2];
  const float* wv    = (const float*)d_in[3];
  const float* bv    = (const float*)d_in[4];
  const float* wt    = (const float*)d_in[5];
  const float* bt    = (const float*)d_in[6];
  const float* gamma = (const float*)d_in[7];
  const float* beta  = (const float*)d_in[8];
  char* ws = (char*)d_ws;

  // Region A [0, 64MB): atom16; attn reads atom16[idx] then writes xt[idx] (same thread,
  // read-before-write) -> safe in-place. Region B [64MB, 160MB): qkv (dead after attn) -> tmat.
  __bf16* atom16 = (__bf16*)(ws);                    // 67,108,864 B
  __bf16* xtr    = (__bf16*)(ws);                    // in-place over atom16
  __bf16* qkv    = (__bf16*)(ws + 67108864);         // 100,663,296 B
  __bf16* tmat   = (__bf16*)(ws + 67108864);         // overlaps qkv (dead)
  __bf16* wqkv16 = (__bf16*)(ws + 167772160);        // 786,432 B
  __bf16* wt16   = (__bf16*)(ws + 168558592);        // 524,288 B
  float*  bqkv   = (float*)(ws + 169082880);         // 3,072 B
  float*  stats  = (float*)(ws + 169085952);         // 4,096 B
  float*  out    = (float*)d_out;

  k_prep<<<dim3(2048), dim3(256), 0, stream>>>(atom, wqk, bqk, wv, bv, wt,
                                               atom16, wqkv16, bqkv, wt16, stats);
  k_gemm<NQKV, false><<<dim3(512, 3), dim3(512), 0, stream>>>(atom16, wqkv16, bqkv, qkv, nullptr);
  k_attn<<<dim3(1024), dim3(256), 0, stream>>>(qkv, atom16, xtr);
  k_gemm<CH, true><<<dim3(512, 2), dim3(512), 0, stream>>>(xtr, wt16, bt, tmat, stats);
  k_final<<<dim3(2048), dim3(256), 0, stream>>>(atom, tmat, stats, gamma, beta, out);
}